// Round 14
// baseline (108.408 us; speedup 1.0000x reference)
//
#include <hip/hip_runtime.h>

#define NVV   778
#define NSEG  16
#define SEGSZ 49
#define GRIDN 32
#define BATCH 128
#define NPTS  (NSEG * SEGSZ)           // 784
#define VOLSZ (GRIDN * GRIDN * GRIDN)  // 32768 floats = 128 KB
#define NBLK  256
#define VPB   16                        // volumes per persistent block

// clean 16/16 z-split: B0 = slabs 0..15, B1 = slabs 16..31 (64 KB each)
#define HF (16 * 1024)

// Producer-wave register staging: 8 named float4 loads then 8 ds_writes
// (64 KB per phase over 8 producer waves; wave wv owns an 8 KB span).
// The ds_write is the load's use, so hipcc cannot sink the loads (R5/R6
// failure) and emits counted vmcnt(7..0) between load and write — the
// m201 stage pattern. R13 lesson: the global_load_lds DMA path streams
// ~15% slower per byte than this reg path (R2 evidence: 6.8 vs 5.8 TB/s).
#define STAGE(DST, SRC) { \
    const float* s_ = (SRC) + (wv << 11) + (lane << 2); \
    float*       d_ = (DST) + (wv << 11) + (lane << 2); \
    float4 c0 = *(const float4*)(s_ + 0 * 256); \
    float4 c1 = *(const float4*)(s_ + 1 * 256); \
    float4 c2 = *(const float4*)(s_ + 2 * 256); \
    float4 c3 = *(const float4*)(s_ + 3 * 256); \
    float4 c4 = *(const float4*)(s_ + 4 * 256); \
    float4 c5 = *(const float4*)(s_ + 5 * 256); \
    float4 c6 = *(const float4*)(s_ + 6 * 256); \
    float4 c7 = *(const float4*)(s_ + 7 * 256); \
    *(float4*)(d_ + 0 * 256) = c0; \
    *(float4*)(d_ + 1 * 256) = c1; \
    *(float4*)(d_ + 2 * 256) = c2; \
    *(float4*)(d_ + 3 * 256) = c3; \
    *(float4*)(d_ + 4 * 256) = c4; \
    *(float4*)(d_ + 5 * 256) = c5; \
    *(float4*)(d_ + 6 * 256) = c6; \
    *(float4*)(d_ + 7 * 256) = c7; }

// 2x2 xy-taps within one z-slab
__device__ __forceinline__ float tapxy(const float* slab, int x0, int y0,
                                       float wx, float wy)
{
    float s = 0.f;
    #pragma unroll
    for (int dy = 0; dy < 2; ++dy) {
        int yy = y0 + dy;
        if (yy < 0 || yy >= GRIDN) continue;
        float wyv = dy ? wy : 1.f - wy;
        const float* row = slab + yy * GRIDN;
        #pragma unroll
        for (int dx = 0; dx < 2; ++dx) {
            int xx = x0 + dx;
            if (xx < 0 || xx >= GRIDN) continue;
            s += wyv * (dx ? wx : 1.f - wx) * row[xx];
        }
    }
    return s;
}

// Persistent: 256 blocks x 1024 threads (1 block/CU, ~128 KB LDS).
// Waves 0-7 = producers (vector-load -> ds_write staging only, no taps),
// waves 8-15 = consumers (taps only, no staging). Phase A: producers
// stage h1(v)->B1, consumers tap h0(v) in B0. Phase B: producers stage
// h0(v+1)->B0, consumers tap h1(v) in B1. Plain __syncthreads (each
// wave's vmem is already retired by its own ds_writes -> cheap). One
// deferred atomic per volume (R10 lesson: hot-address atomics serialize).
__global__ __launch_bounds__(1024, 4) void sample_kernel(
    const float* __restrict__ vertices, const int* __restrict__ seg,
    const float* __restrict__ phiR, const float* __restrict__ phiL,
    float* __restrict__ loss)
{
    __shared__ __align__(16) float B0[HF];
    __shared__ __align__(16) float B1[HF];
    __shared__ float4 sbox[VPB];
    __shared__ float wsum[8];

    const int tid  = threadIdx.x;
    const int bx   = blockIdx.x;
    const int k    = bx & (NSEG - 1);    // constant per block (256 % 16 == 0)
    const int wv   = tid >> 6;           // 0..7 producers, 8..15 consumers
    const int lane = tid & 63;
    const bool producer = (wv < 8);
    const int ct   = tid - 512;          // consumer thread id [0,512)

    auto phiPtr = [&](int it) {
        int vid  = bx + NBLK * it;
        int b    = (vid >> 4) & (BATCH - 1);
        int pass = vid >> 11;            // NSEG*BATCH = 2048
        return (pass == 0 ? phiR : phiL) + ((size_t)k * BATCH + b) * VOLSZ;
    };
    auto vertBase = [&](int it) {
        int vid  = bx + NBLK * it;
        int b    = (vid >> 4) & (BATCH - 1);
        int srcS = (vid >> 11) == 0 ? 1 : 0;   // pass0 samples LEFT verts
        return vertices + ((size_t)b * 2 + srcS) * NVV * 3;
    };

    // ---- prologue ----
    int pvi1 = 0, pvi2 = 0;
    bool has2 = false;
    if (!producer) {
        pvi1 = seg[ct];
        has2 = (ct + 512) < NPTS;
        pvi2 = has2 ? seg[ct + 512] : 0;
    }

    // boxes: wave wv computes volume wv's box (all 16 waves)
    {
        int vidw    = bx + NBLK * wv;
        int bbw     = (vidw >> 4) & (BATCH - 1);
        int boxSide = ((vidw >> 11) == 0) ? 0 : 1;   // opposite of sampled
        bool bact   = lane < SEGSZ;
        int bvi     = bact ? seg[k * SEGSZ + lane] : 0;
        const float* bvp = vertices + (((size_t)bbw * 2 + boxSide) * NVV + bvi) * 3;
        float x = bvp[0], y = bvp[1], z = bvp[2];
        float mnx = bact ? x : 1e30f, mxx = bact ? x : -1e30f;
        float mny = bact ? y : 1e30f, mxy = bact ? y : -1e30f;
        float mnz = bact ? z : 1e30f, mxz = bact ? z : -1e30f;
        #pragma unroll
        for (int m = 32; m; m >>= 1) {
            mnx = fminf(mnx, __shfl_xor(mnx, m));
            mxx = fmaxf(mxx, __shfl_xor(mxx, m));
            mny = fminf(mny, __shfl_xor(mny, m));
            mxy = fmaxf(mxy, __shfl_xor(mxy, m));
            mnz = fminf(mnz, __shfl_xor(mnz, m));
            mxz = fmaxf(mxz, __shfl_xor(mxz, m));
        }
        if (lane == 0) {
            float ext = fmaxf(fmaxf(mxx - mnx, mxy - mny), mxz - mnz);
            sbox[wv] = make_float4(0.5f * (mnx + mxx), 0.5f * (mny + mxy),
                                   0.5f * (mnz + mxz), 1.0f / (0.55f * ext));
        }
    }

    // volume-0 point coords (consumers)
    float p1x = 0.f, p1y = 0.f, p1z = 0.f;
    float p2x = 0.f, p2y = 0.f, p2z = 0.f;
    if (!producer) {
        const float* vb = vertBase(0);
        p1x = vb[pvi1 * 3 + 0]; p1y = vb[pvi1 * 3 + 1]; p1z = vb[pvi1 * 3 + 2];
        if (has2) {
            p2x = vb[pvi2 * 3 + 0]; p2y = vb[pvi2 * 3 + 1]; p2z = vb[pvi2 * 3 + 2];
        }
    }

    // producers: stage h0(volume 0) into B0
    if (producer) { STAGE(B0, phiPtr(0)) }

    __syncthreads();   // B0 resident, sbox visible

    float n1x = 0.f, n1y = 0.f, n1z = 0.f;
    float n2x = 0.f, n2y = 0.f, n2z = 0.f;

    for (int v = 0; v < VPB; ++v) {
        const bool more = (v + 1 < VPB);

        // per-point per-volume state (registers, live across both phases)
        float f1x = 0.f, f1y = 0.f, f1z = -2.f;
        float f2x = 0.f, f2y = 0.f, f2z = -2.f;
        if (!producer) {
            float4 b4 = sbox[v];
            f1x = ((p1x - b4.x) * b4.w + 1.f) * 15.5f;
            f1y = ((p1y - b4.y) * b4.w + 1.f) * 15.5f;
            f1z = ((p1z - b4.z) * b4.w + 1.f) * 15.5f;
            if (has2) {
                f2x = ((p2x - b4.x) * b4.w + 1.f) * 15.5f;
                f2y = ((p2y - b4.y) * b4.w + 1.f) * 15.5f;
                f2z = ((p2z - b4.z) * b4.w + 1.f) * 15.5f;
            }
        }
        bool a1 = (f1x > -1.f && f1x < 32.f && f1y > -1.f && f1y < 32.f &&
                   f1z > -1.f && f1z < 32.f);
        bool a2 = (f2x > -1.f && f2x < 32.f && f2y > -1.f && f2y < 32.f &&
                   f2z > -1.f && f2z < 32.f);
        float x1f = floorf(f1x), y1f = floorf(f1y), z1f = floorf(f1z);
        float x2f = floorf(f2x), y2f = floorf(f2y), z2f = floorf(f2z);
        float w1x = f1x - x1f, w1y = f1y - y1f, w1z = f1z - z1f;
        float w2x = f2x - x2f, w2y = f2y - y2f, w2z = f2z - z2f;
        int x1 = (int)x1f, y1 = (int)y1f, z1 = (int)z1f;
        int x2 = (int)x2f, y2 = (int)y2f, z2 = (int)z2f;
        float acc1 = 0.f, acc2 = 0.f;

        // ===== phase A: producers stage h1(v) -> B1; consumers tap B0 ===
        if (producer) {
            STAGE(B1, phiPtr(v) + HF)
        } else {
            // deferred single atomic for volume v-1
            if (v > 0 && ct == 0) {
                float tot = 0.f;
                #pragma unroll
                for (int i = 0; i < 8; ++i) tot += wsum[i];
                int vidp = bx + NBLK * (v - 1);
                atomicAdd(loss + ((vidp >> 4) & (BATCH - 1)), tot * 0.25f);
            }
            if (a1 && z1 <= 15) {
                if (z1 >= 0)
                    acc1 += (1.f - w1z) * tapxy(B0 + z1 * 1024, x1, y1, w1x, w1y);
                if (z1 <= 14)
                    acc1 += w1z * tapxy(B0 + (z1 + 1) * 1024, x1, y1, w1x, w1y);
            }
            if (a2 && z2 <= 15) {
                if (z2 >= 0)
                    acc2 += (1.f - w2z) * tapxy(B0 + z2 * 1024, x2, y2, w2x, w2y);
                if (z2 <= 14)
                    acc2 += w2z * tapxy(B0 + (z2 + 1) * 1024, x2, y2, w2x, w2y);
            }
            // next volume's point coords (retire by v+1's use)
            if (more) {
                const float* vb = vertBase(v + 1);
                n1x = vb[pvi1 * 3 + 0]; n1y = vb[pvi1 * 3 + 1]; n1z = vb[pvi1 * 3 + 2];
                if (has2) {
                    n2x = vb[pvi2 * 3 + 0]; n2y = vb[pvi2 * 3 + 1]; n2z = vb[pvi2 * 3 + 2];
                }
            }
        }
        __syncthreads();   // B1 resident; B0 consumed

        // ===== phase B: producers stage h0(v+1) -> B0; consumers tap B1 =
        if (producer) {
            if (more) { STAGE(B0, phiPtr(v + 1)) }
        } else {
            if (a1 && z1 >= 15) {
                if (z1 >= 16)
                    acc1 += (1.f - w1z) * tapxy(B1 + (z1 - 16) * 1024, x1, y1, w1x, w1y);
                if (z1 <= 30)
                    acc1 += w1z * tapxy(B1 + (z1 - 15) * 1024, x1, y1, w1x, w1y);
            }
            if (a2 && z2 >= 15) {
                if (z2 >= 16)
                    acc2 += (1.f - w2z) * tapxy(B1 + (z2 - 16) * 1024, x2, y2, w2x, w2y);
                if (z2 <= 30)
                    acc2 += w2z * tapxy(B1 + (z2 - 15) * 1024, x2, y2, w2x, w2y);
            }
            float acc = acc1 + acc2;
            #pragma unroll
            for (int off = 32; off; off >>= 1)
                acc += __shfl_down(acc, off);
            if (lane == 0) wsum[wv - 8] = acc;
        }
        __syncthreads();   // B0 resident; B1 consumed; wsum visible
        p1x = n1x; p1y = n1y; p1z = n1z;
        p2x = n2x; p2y = n2y; p2z = n2z;
    }

    // final volume's atomic
    if (!producer && ct == 0) {
        float tot = 0.f;
        #pragma unroll
        for (int i = 0; i < 8; ++i) tot += wsum[i];
        int vidp = bx + NBLK * (VPB - 1);
        atomicAdd(loss + ((vidp >> 4) & (BATCH - 1)), tot * 0.25f);
    }
}

extern "C" void kernel_launch(void* const* d_in, const int* in_sizes, int n_in,
                              void* d_out, int out_size, void* d_ws, size_t ws_size,
                              hipStream_t stream) {
    const float* vertices = (const float*)d_in[0];
    const float* phiR     = (const float*)d_in[1];
    const float* phiL     = (const float*)d_in[2];
    const int*   seg      = (const int*)d_in[3];
    float* loss = (float*)d_out;

    hipMemsetAsync(d_out, 0, (size_t)out_size * sizeof(float), stream);

    sample_kernel<<<NBLK, 1024, 0, stream>>>(vertices, seg, phiR, phiL, loss);
}

// Round 15
// 102.319 us; speedup vs baseline: 1.0595x; 1.0595x over previous
//
#include <hip/hip_runtime.h>

#define NVV   778
#define NSEG  16
#define SEGSZ 49
#define GRIDN 32
#define BATCH 128
#define NPTS  (NSEG * SEGSZ)           // 784
#define VOLSZ (GRIDN * GRIDN * GRIDN)  // 32768 floats = 128 KB
#define NBLK  256
#define VPB   16                        // volumes per persistent block

// clean 16/16 z-split: B0 = slabs 0..15, B1 = slabs 16..31 (64 KB each)
#define HF (16 * 1024)

typedef float f4v __attribute__((ext_vector_type(4)));

// R15 A/B: NON-TEMPORAL staging loads (nt: no L2/L3 allocation). All six
// prior schedules converged at 106-108us with ~50% of phi served from L3
// (FETCH 278 of 537 MB). If the L3-hit return path is the per-CU
// throughput limiter, nt forces pure-HBM streaming at copy-rate.
#define NTLD(p) __builtin_nontemporal_load((const f4v*)(p))

#define STAGE(DST, SRC) { \
    const float* s_ = (SRC) + (wv << 11) + (lane << 2); \
    float*       d_ = (DST) + (wv << 11) + (lane << 2); \
    f4v c0 = NTLD(s_ + 0 * 256); \
    f4v c1 = NTLD(s_ + 1 * 256); \
    f4v c2 = NTLD(s_ + 2 * 256); \
    f4v c3 = NTLD(s_ + 3 * 256); \
    f4v c4 = NTLD(s_ + 4 * 256); \
    f4v c5 = NTLD(s_ + 5 * 256); \
    f4v c6 = NTLD(s_ + 6 * 256); \
    f4v c7 = NTLD(s_ + 7 * 256); \
    *(f4v*)(d_ + 0 * 256) = c0; \
    *(f4v*)(d_ + 1 * 256) = c1; \
    *(f4v*)(d_ + 2 * 256) = c2; \
    *(f4v*)(d_ + 3 * 256) = c3; \
    *(f4v*)(d_ + 4 * 256) = c4; \
    *(f4v*)(d_ + 5 * 256) = c5; \
    *(f4v*)(d_ + 6 * 256) = c6; \
    *(f4v*)(d_ + 7 * 256) = c7; }

// 2x2 xy-taps within one z-slab
__device__ __forceinline__ float tapxy(const float* slab, int x0, int y0,
                                       float wx, float wy)
{
    float s = 0.f;
    #pragma unroll
    for (int dy = 0; dy < 2; ++dy) {
        int yy = y0 + dy;
        if (yy < 0 || yy >= GRIDN) continue;
        float wyv = dy ? wy : 1.f - wy;
        const float* row = slab + yy * GRIDN;
        #pragma unroll
        for (int dx = 0; dx < 2; ++dx) {
            int xx = x0 + dx;
            if (xx < 0 || xx >= GRIDN) continue;
            s += wyv * (dx ? wx : 1.f - wx) * row[xx];
        }
    }
    return s;
}

// Persistent: 256 blocks x 1024 threads (1 block/CU, ~128 KB LDS).
// Waves 0-7 = producers (nt vector-load -> ds_write staging), waves 8-15 =
// consumers (taps). Phase A: stage h1(v)->B1 while tapping h0(v) in B0;
// phase B: stage h0(v+1)->B0 while tapping h1(v) in B1. One deferred
// atomic per volume (R10 lesson: hot-address atomics serialize 256 waves).
__global__ __launch_bounds__(1024, 4) void sample_kernel(
    const float* __restrict__ vertices, const int* __restrict__ seg,
    const float* __restrict__ phiR, const float* __restrict__ phiL,
    float* __restrict__ loss)
{
    __shared__ __align__(16) float B0[HF];
    __shared__ __align__(16) float B1[HF];
    __shared__ float4 sbox[VPB];
    __shared__ float wsum[8];

    const int tid  = threadIdx.x;
    const int bx   = blockIdx.x;
    const int k    = bx & (NSEG - 1);    // constant per block (256 % 16 == 0)
    const int wv   = tid >> 6;           // 0..7 producers, 8..15 consumers
    const int lane = tid & 63;
    const bool producer = (wv < 8);
    const int ct   = tid - 512;          // consumer thread id [0,512)

    auto phiPtr = [&](int it) {
        int vid  = bx + NBLK * it;
        int b    = (vid >> 4) & (BATCH - 1);
        int pass = vid >> 11;            // NSEG*BATCH = 2048
        return (pass == 0 ? phiR : phiL) + ((size_t)k * BATCH + b) * VOLSZ;
    };
    auto vertBase = [&](int it) {
        int vid  = bx + NBLK * it;
        int b    = (vid >> 4) & (BATCH - 1);
        int srcS = (vid >> 11) == 0 ? 1 : 0;   // pass0 samples LEFT verts
        return vertices + ((size_t)b * 2 + srcS) * NVV * 3;
    };

    // ---- prologue ----
    int pvi1 = 0, pvi2 = 0;
    bool has2 = false;
    if (!producer) {
        pvi1 = seg[ct];
        has2 = (ct + 512) < NPTS;
        pvi2 = has2 ? seg[ct + 512] : 0;
    }

    // boxes: wave wv computes volume wv's box (all 16 waves)
    {
        int vidw    = bx + NBLK * wv;
        int bbw     = (vidw >> 4) & (BATCH - 1);
        int boxSide = ((vidw >> 11) == 0) ? 0 : 1;   // opposite of sampled
        bool bact   = lane < SEGSZ;
        int bvi     = bact ? seg[k * SEGSZ + lane] : 0;
        const float* bvp = vertices + (((size_t)bbw * 2 + boxSide) * NVV + bvi) * 3;
        float x = bvp[0], y = bvp[1], z = bvp[2];
        float mnx = bact ? x : 1e30f, mxx = bact ? x : -1e30f;
        float mny = bact ? y : 1e30f, mxy = bact ? y : -1e30f;
        float mnz = bact ? z : 1e30f, mxz = bact ? z : -1e30f;
        #pragma unroll
        for (int m = 32; m; m >>= 1) {
            mnx = fminf(mnx, __shfl_xor(mnx, m));
            mxx = fmaxf(mxx, __shfl_xor(mxx, m));
            mny = fminf(mny, __shfl_xor(mny, m));
            mxy = fmaxf(mxy, __shfl_xor(mxy, m));
            mnz = fminf(mnz, __shfl_xor(mnz, m));
            mxz = fmaxf(mxz, __shfl_xor(mxz, m));
        }
        if (lane == 0) {
            float ext = fmaxf(fmaxf(mxx - mnx, mxy - mny), mxz - mnz);
            sbox[wv] = make_float4(0.5f * (mnx + mxx), 0.5f * (mny + mxy),
                                   0.5f * (mnz + mxz), 1.0f / (0.55f * ext));
        }
    }

    // volume-0 point coords (consumers)
    float p1x = 0.f, p1y = 0.f, p1z = 0.f;
    float p2x = 0.f, p2y = 0.f, p2z = 0.f;
    if (!producer) {
        const float* vb = vertBase(0);
        p1x = vb[pvi1 * 3 + 0]; p1y = vb[pvi1 * 3 + 1]; p1z = vb[pvi1 * 3 + 2];
        if (has2) {
            p2x = vb[pvi2 * 3 + 0]; p2y = vb[pvi2 * 3 + 1]; p2z = vb[pvi2 * 3 + 2];
        }
    }

    // producers: stage h0(volume 0) into B0
    if (producer) { STAGE(B0, phiPtr(0)) }

    __syncthreads();   // B0 resident, sbox visible

    float n1x = 0.f, n1y = 0.f, n1z = 0.f;
    float n2x = 0.f, n2y = 0.f, n2z = 0.f;

    for (int v = 0; v < VPB; ++v) {
        const bool more = (v + 1 < VPB);

        // per-point per-volume state (registers, live across both phases)
        float f1x = 0.f, f1y = 0.f, f1z = -2.f;
        float f2x = 0.f, f2y = 0.f, f2z = -2.f;
        if (!producer) {
            float4 b4 = sbox[v];
            f1x = ((p1x - b4.x) * b4.w + 1.f) * 15.5f;
            f1y = ((p1y - b4.y) * b4.w + 1.f) * 15.5f;
            f1z = ((p1z - b4.z) * b4.w + 1.f) * 15.5f;
            if (has2) {
                f2x = ((p2x - b4.x) * b4.w + 1.f) * 15.5f;
                f2y = ((p2y - b4.y) * b4.w + 1.f) * 15.5f;
                f2z = ((p2z - b4.z) * b4.w + 1.f) * 15.5f;
            }
        }
        bool a1 = (f1x > -1.f && f1x < 32.f && f1y > -1.f && f1y < 32.f &&
                   f1z > -1.f && f1z < 32.f);
        bool a2 = (f2x > -1.f && f2x < 32.f && f2y > -1.f && f2y < 32.f &&
                   f2z > -1.f && f2z < 32.f);
        float x1f = floorf(f1x), y1f = floorf(f1y), z1f = floorf(f1z);
        float x2f = floorf(f2x), y2f = floorf(f2y), z2f = floorf(f2z);
        float w1x = f1x - x1f, w1y = f1y - y1f, w1z = f1z - z1f;
        float w2x = f2x - x2f, w2y = f2y - y2f, w2z = f2z - z2f;
        int x1 = (int)x1f, y1 = (int)y1f, z1 = (int)z1f;
        int x2 = (int)x2f, y2 = (int)y2f, z2 = (int)z2f;
        float acc1 = 0.f, acc2 = 0.f;

        // ===== phase A: producers stage h1(v) -> B1; consumers tap B0 ===
        if (producer) {
            STAGE(B1, phiPtr(v) + HF)
        } else {
            if (v > 0 && ct == 0) {      // deferred atomic for volume v-1
                float tot = 0.f;
                #pragma unroll
                for (int i = 0; i < 8; ++i) tot += wsum[i];
                int vidp = bx + NBLK * (v - 1);
                atomicAdd(loss + ((vidp >> 4) & (BATCH - 1)), tot * 0.25f);
            }
            if (a1 && z1 <= 15) {
                if (z1 >= 0)
                    acc1 += (1.f - w1z) * tapxy(B0 + z1 * 1024, x1, y1, w1x, w1y);
                if (z1 <= 14)
                    acc1 += w1z * tapxy(B0 + (z1 + 1) * 1024, x1, y1, w1x, w1y);
            }
            if (a2 && z2 <= 15) {
                if (z2 >= 0)
                    acc2 += (1.f - w2z) * tapxy(B0 + z2 * 1024, x2, y2, w2x, w2y);
                if (z2 <= 14)
                    acc2 += w2z * tapxy(B0 + (z2 + 1) * 1024, x2, y2, w2x, w2y);
            }
            if (more) {                  // next volume's point coords
                const float* vb = vertBase(v + 1);
                n1x = vb[pvi1 * 3 + 0]; n1y = vb[pvi1 * 3 + 1]; n1z = vb[pvi1 * 3 + 2];
                if (has2) {
                    n2x = vb[pvi2 * 3 + 0]; n2y = vb[pvi2 * 3 + 1]; n2z = vb[pvi2 * 3 + 2];
                }
            }
        }
        __syncthreads();   // B1 resident; B0 consumed

        // ===== phase B: producers stage h0(v+1) -> B0; consumers tap B1 =
        if (producer) {
            if (more) { STAGE(B0, phiPtr(v + 1)) }
        } else {
            if (a1 && z1 >= 15) {
                if (z1 >= 16)
                    acc1 += (1.f - w1z) * tapxy(B1 + (z1 - 16) * 1024, x1, y1, w1x, w1y);
                if (z1 <= 30)
                    acc1 += w1z * tapxy(B1 + (z1 - 15) * 1024, x1, y1, w1x, w1y);
            }
            if (a2 && z2 >= 15) {
                if (z2 >= 16)
                    acc2 += (1.f - w2z) * tapxy(B1 + (z2 - 16) * 1024, x2, y2, w2x, w2y);
                if (z2 <= 30)
                    acc2 += w2z * tapxy(B1 + (z2 - 15) * 1024, x2, y2, w2x, w2y);
            }
            float acc = acc1 + acc2;
            #pragma unroll
            for (int off = 32; off; off >>= 1)
                acc += __shfl_down(acc, off);
            if (lane == 0) wsum[wv - 8] = acc;
        }
        __syncthreads();   // B0 resident; B1 consumed; wsum visible
        p1x = n1x; p1y = n1y; p1z = n1z;
        p2x = n2x; p2y = n2y; p2z = n2z;
    }

    // final volume's atomic
    if (!producer && ct == 0) {
        float tot = 0.f;
        #pragma unroll
        for (int i = 0; i < 8; ++i) tot += wsum[i];
        int vidp = bx + NBLK * (VPB - 1);
        atomicAdd(loss + ((vidp >> 4) & (BATCH - 1)), tot * 0.25f);
    }
}

extern "C" void kernel_launch(void* const* d_in, const int* in_sizes, int n_in,
                              void* d_out, int out_size, void* d_ws, size_t ws_size,
                              hipStream_t stream) {
    const float* vertices = (const float*)d_in[0];
    const float* phiR     = (const float*)d_in[1];
    const float* phiL     = (const float*)d_in[2];
    const int*   seg      = (const int*)d_in[3];
    float* loss = (float*)d_out;

    hipMemsetAsync(d_out, 0, (size_t)out_size * sizeof(float), stream);

    sample_kernel<<<NBLK, 1024, 0, stream>>>(vertices, seg, phiR, phiL, loss);
}